// Round 1
// baseline (5716.448 us; speedup 1.0000x reference)
//
#include <hip/hip_runtime.h>
#include <hip/hip_bf16.h>
#include <cstddef>

// Problem constants (fixed by the reference)
#define BATCH 2
#define SEQ   2048
#define DIM   2048
#define HEADS 16
#define DHEAD 128
#define INNER (HEADS * DHEAD)   // 2048
#define MROWS (BATCH * SEQ)     // 4096
#define ATT_SCALE 0.08838834764831845f  // 128^-0.5
#define NEG_LOG2_10000_DIV64 (-13.287712379549449f / 64.0f)

// ---------------------------------------------------------------------------
// Tiled fp32 SGEMM: C[M,N] = A[M,K] @ B[K,N], all row-major.
// BM=BN=64, BK=16, 256 threads, 4x4 micro-tile per thread.
// M,N multiples of 64; K multiple of 16 (true for all three calls).
// ---------------------------------------------------------------------------
#define BM 64
#define BN 64
#define BK 16

__global__ __launch_bounds__(256) void sgemm64(const float* __restrict__ A,
                                               const float* __restrict__ B,
                                               float* __restrict__ C,
                                               int M, int N, int K) {
    __shared__ float As[BK][BM];   // stored K-major to avoid conflicts on compute reads
    __shared__ float Bs[BK][BN];

    const int tid = threadIdx.x;
    const int tx = tid & 15;       // N-dir
    const int ty = tid >> 4;       // M-dir
    const int bm = blockIdx.y * BM;
    const int bn = blockIdx.x * BN;

    // global->LDS load indices
    const int arow = tid >> 2;        // 0..63
    const int acol = (tid & 3) * 4;   // 0,4,8,12
    const int brow = tid >> 4;        // 0..15
    const int bcol = (tid & 15) * 4;  // 0..60

    float acc[4][4] = {};

    for (int k0 = 0; k0 < K; k0 += BK) {
        float4 av = *(const float4*)&A[(size_t)(bm + arow) * K + k0 + acol];
        float4 bv = *(const float4*)&B[(size_t)(k0 + brow) * N + bn + bcol];
        __syncthreads();   // previous iteration's compute done before overwrite
        As[acol + 0][arow] = av.x;
        As[acol + 1][arow] = av.y;
        As[acol + 2][arow] = av.z;
        As[acol + 3][arow] = av.w;
        *(float4*)&Bs[brow][bcol] = bv;
        __syncthreads();
#pragma unroll
        for (int k = 0; k < BK; ++k) {
            float am[4], bnv[4];
#pragma unroll
            for (int m = 0; m < 4; ++m) am[m] = As[k][ty * 4 + m];
#pragma unroll
            for (int n = 0; n < 4; ++n) bnv[n] = Bs[k][tx * 4 + n];
#pragma unroll
            for (int m = 0; m < 4; ++m)
#pragma unroll
                for (int n = 0; n < 4; ++n)
                    acc[m][n] += am[m] * bnv[n];
        }
    }

#pragma unroll
    for (int m = 0; m < 4; ++m) {
        float4 v = make_float4(acc[m][0], acc[m][1], acc[m][2], acc[m][3]);
        *(float4*)&C[(size_t)(bm + ty * 4 + m) * N + bn + tx * 4] = v;
    }
}

// ---------------------------------------------------------------------------
// In-place RoPE on q (layout [b, pos, h, d], contiguous [MROWS, INNER]).
// One thread per (row, head, j) pair with j in [0,64): handles d=j and d=j+64.
//   out[j]    = t[j]*cos - t[j+64]*sin
//   out[j+64] = t[j+64]*cos + t[j]*sin
// Also applies the 1/sqrt(d) scale (reference scales q after rope).
// ---------------------------------------------------------------------------
__global__ __launch_bounds__(256) void rope_q_inplace(float* __restrict__ q) {
    int idx = blockIdx.x * 256 + threadIdx.x;        // over MROWS*HEADS*64
    int j = idx & 63;
    int rh = idx >> 6;                               // (b*SEQ+pos)*HEADS + h
    int pos = (rh >> 4) & (SEQ - 1);
    float* row = q + ((size_t)rh << 7);              // *128
    float a = row[j];
    float b = row[j + 64];
    float ang = (float)pos * exp2f((float)j * NEG_LOG2_10000_DIV64);
    float c = cosf(ang), s = sinf(ang);
    row[j]      = (a * c - b * s) * ATT_SCALE;
    row[j + 64] = (b * c + a * s) * ATT_SCALE;
}

// In-place RoPE on k, which lives in the kv buffer [b, pos, 256] (k = [:128]).
__global__ __launch_bounds__(256) void rope_k_inplace(float* __restrict__ kvb) {
    int idx = blockIdx.x * 256 + threadIdx.x;        // over BATCH*SEQ*64
    int j = idx & 63;
    int bn = idx >> 6;                               // b*SEQ + pos
    int pos = bn & (SEQ - 1);
    float* row = kvb + (size_t)bn * 256;
    float a = row[j];
    float b = row[j + 64];
    float ang = (float)pos * exp2f((float)j * NEG_LOG2_10000_DIV64);
    float c = cosf(ang), s = sinf(ang);
    row[j]      = a * c - b * s;
    row[j + 64] = b * c + a * s;
}

// ---------------------------------------------------------------------------
// Causal MQA attention, one workgroup (256 threads) per (b, h, query row i).
// q layout [b, pos, h, d]; k/v interleaved in kv buffer [b, pos, 256].
// Scores for j<=i in LDS, two-pass softmax, coalesced v accumulation.
// Writes o in [b, pos, h*d] layout for the output projection.
// ---------------------------------------------------------------------------
__global__ __launch_bounds__(256) void attn_row(const float* __restrict__ q,
                                                const float* __restrict__ kvb,
                                                float* __restrict__ o) {
    const int bid = blockIdx.x;          // (b*HEADS + h)*SEQ + i
    const int i = bid & (SEQ - 1);
    const int bh = bid >> 11;
    const int h = bh & (HEADS - 1);
    const int b = bh >> 4;
    const int t = threadIdx.x;

    __shared__ float qs[DHEAD];
    __shared__ float s[SEQ];
    __shared__ float red[256];

    const float* qrow = q + (((size_t)(b * SEQ + i)) * HEADS + h) * DHEAD;
    if (t < DHEAD) qs[t] = qrow[t];
    __syncthreads();

    // scores s[j] = q_i . k_j  for j <= i
    const float* kb = kvb + (size_t)b * SEQ * 256;
    float lmax = -3.4e38f;
    for (int j = t; j <= i; j += 256) {
        const float4* krow = (const float4*)(kb + (size_t)j * 256);
        const float4* qv4 = (const float4*)qs;
        float dot = 0.f;
#pragma unroll 8
        for (int d4 = 0; d4 < 32; ++d4) {
            float4 kv4 = krow[d4];
            float4 qv = qv4[d4];
            dot += qv.x * kv4.x + qv.y * kv4.y + qv.z * kv4.z + qv.w * kv4.w;
        }
        s[j] = dot;
        lmax = fmaxf(lmax, dot);
    }

    // block max
    red[t] = lmax;
    __syncthreads();
    for (int off = 128; off > 0; off >>= 1) {
        if (t < off) red[t] = fmaxf(red[t], red[t + off]);
        __syncthreads();
    }
    const float m = red[0];
    __syncthreads();

    // exp + block sum
    float lsum = 0.f;
    for (int j = t; j <= i; j += 256) {
        float e = __expf(s[j] - m);
        s[j] = e;
        lsum += e;
    }
    red[t] = lsum;
    __syncthreads();
    for (int off = 128; off > 0; off >>= 1) {
        if (t < off) red[t] += red[t + off];
        __syncthreads();
    }
    const float inv = 1.f / red[0];
    __syncthreads();

    // o[d] = sum_j p_j * v[j][d]; two thread-groups split j parity
    const int g = t >> 7;        // 0 or 1
    const int d = t & 127;
    const float* vb = kb + 128 + d;    // v at offset 128 within each 256-row
    float acc = 0.f;
#pragma unroll 4
    for (int j = g; j <= i; j += 2) {
        acc += s[j] * vb[(size_t)j * 256];
    }
    red[t] = acc;
    __syncthreads();
    if (t < 128) {
        float res = (red[t] + red[t + 128]) * inv;
        o[((size_t)(b * SEQ + i)) * INNER + h * DHEAD + t] = res;
    }
}

// ---------------------------------------------------------------------------
extern "C" void kernel_launch(void* const* d_in, const int* in_sizes, int n_in,
                              void* d_out, int out_size, void* d_ws, size_t ws_size,
                              hipStream_t stream) {
    const float* x    = (const float*)d_in[0];   // [2, 2048, 2048]
    const float* Wq   = (const float*)d_in[1];   // [2048, 2048]
    const float* Wkv  = (const float*)d_in[2];   // [2048, 256]
    const float* Wout = (const float*)d_in[3];   // [2048, 2048]
    float* out = (float*)d_out;                  // [2, 2048, 2048]

    // workspace layout (floats)
    float* q   = (float*)d_ws;                         // MROWS*INNER  (33.5 MB)
    float* kvb = q + (size_t)MROWS * INNER;            // MROWS*256    ( 4  MB)
    float* o   = kvb + (size_t)MROWS * 256;            // MROWS*INNER  (33.5 MB)

    // 1) q = x @ Wq   [4096,2048]@[2048,2048]
    sgemm64<<<dim3(INNER / BN, MROWS / BM), 256, 0, stream>>>(x, Wq, q, MROWS, INNER, DIM);
    // 2) kv = x @ Wkv [4096,2048]@[2048,256]
    sgemm64<<<dim3(256 / BN, MROWS / BM), 256, 0, stream>>>(x, Wkv, kvb, MROWS, 256, DIM);
    // 3) RoPE q (in-place, pair-safe) + scale
    rope_q_inplace<<<(MROWS * HEADS * 64) / 256, 256, 0, stream>>>(q);
    // 4) RoPE k (in-place inside kv buffer)
    rope_k_inplace<<<(BATCH * SEQ * 64) / 256, 256, 0, stream>>>(kvb);
    // 5) causal MQA attention, one block per (b,h,i)
    attn_row<<<BATCH * HEADS * SEQ, 256, 0, stream>>>(q, kvb, o);
    // 6) out = o @ Wout [4096,2048]@[2048,2048]
    sgemm64<<<dim3(DIM / BN, MROWS / BM), 256, 0, stream>>>(o, Wout, out, MROWS, DIM, INNER);
}

// Round 2
// 1285.615 us; speedup vs baseline: 4.4465x; 4.4465x over previous
//
#include <hip/hip_runtime.h>
#include <hip/hip_bf16.h>
#include <cstddef>
#include <cstdint>

// Problem constants (fixed by the reference)
#define BATCH 2
#define SEQ   2048
#define DIM   2048
#define HEADS 16
#define DHEAD 128
#define INNER (HEADS * DHEAD)   // 2048
#define MROWS (BATCH * SEQ)     // 4096
#define ATT_SCALE 0.08838834764831845f  // 128^-0.5
#define NEG_LOG2_10000_DIV64 (-13.287712379549449f / 64.0f)

typedef __attribute__((ext_vector_type(8))) short short8;  // 8 bf16 = 4 VGPRs
typedef __attribute__((ext_vector_type(4))) float f32x4;   // MFMA C/D

// fp32 -> bf16 round-to-nearest-even, bit-level (no API type surprises)
static __device__ __forceinline__ short f2bf(float x) {
    uint32_t u = __float_as_uint(x);
    uint32_t r = (u + 0x7fffu + ((u >> 16) & 1u)) >> 16;
    return (short)r;
}

// ---------------------------------------------------------------------------
// Tiled fp32 SGEMM: C[M,N] = A[M,K] @ B[K,N], all row-major. (unchanged)
// ---------------------------------------------------------------------------
#define BM 64
#define BN 64
#define BK 16

__global__ __launch_bounds__(256) void sgemm64(const float* __restrict__ A,
                                               const float* __restrict__ B,
                                               float* __restrict__ C,
                                               int M, int N, int K) {
    __shared__ float As[BK][BM];
    __shared__ float Bs[BK][BN];

    const int tid = threadIdx.x;
    const int tx = tid & 15;
    const int ty = tid >> 4;
    const int bm = blockIdx.y * BM;
    const int bn = blockIdx.x * BN;

    const int arow = tid >> 2;
    const int acol = (tid & 3) * 4;
    const int brow = tid >> 4;
    const int bcol = (tid & 15) * 4;

    float acc[4][4] = {};

    for (int k0 = 0; k0 < K; k0 += BK) {
        float4 av = *(const float4*)&A[(size_t)(bm + arow) * K + k0 + acol];
        float4 bv = *(const float4*)&B[(size_t)(k0 + brow) * N + bn + bcol];
        __syncthreads();
        As[acol + 0][arow] = av.x;
        As[acol + 1][arow] = av.y;
        As[acol + 2][arow] = av.z;
        As[acol + 3][arow] = av.w;
        *(float4*)&Bs[brow][bcol] = bv;
        __syncthreads();
#pragma unroll
        for (int k = 0; k < BK; ++k) {
            float am[4], bnv[4];
#pragma unroll
            for (int m = 0; m < 4; ++m) am[m] = As[k][ty * 4 + m];
#pragma unroll
            for (int n = 0; n < 4; ++n) bnv[n] = Bs[k][tx * 4 + n];
#pragma unroll
            for (int m = 0; m < 4; ++m)
#pragma unroll
                for (int n = 0; n < 4; ++n)
                    acc[m][n] += am[m] * bnv[n];
        }
    }

#pragma unroll
    for (int m = 0; m < 4; ++m) {
        float4 v = make_float4(acc[m][0], acc[m][1], acc[m][2], acc[m][3]);
        *(float4*)&C[(size_t)(bm + ty * 4 + m) * N + bn + tx * 4] = v;
    }
}

// ---------------------------------------------------------------------------
// RoPE on q (fp32 [MROWS, INNER], layout [b,pos,h,d]) -> bf16 qb, with *SCALE.
// Thread handles the (j, j+64) pair.
// ---------------------------------------------------------------------------
__global__ __launch_bounds__(256) void rope_q_bf16(const float* __restrict__ q,
                                                   short* __restrict__ qb) {
    int idx = blockIdx.x * 256 + threadIdx.x;        // over MROWS*HEADS*64
    int j = idx & 63;
    int rh = idx >> 6;                               // (b*SEQ+pos)*HEADS + h
    int pos = (rh >> 4) & (SEQ - 1);
    const float* row = q + ((size_t)rh << 7);
    short* orow = qb + ((size_t)rh << 7);
    float a = row[j];
    float b = row[j + 64];
    float ang = (float)pos * exp2f((float)j * NEG_LOG2_10000_DIV64);
    float c = cosf(ang), s = sinf(ang);
    orow[j]      = f2bf((a * c - b * s) * ATT_SCALE);
    orow[j + 64] = f2bf((b * c + a * s) * ATT_SCALE);
}

// RoPE on k: reads kv fp32 [b,pos,256] (k = cols 0..127), writes bf16 kb [b,pos,128].
__global__ __launch_bounds__(256) void rope_k_bf16(const float* __restrict__ kvb,
                                                   short* __restrict__ kb) {
    int idx = blockIdx.x * 256 + threadIdx.x;        // over MROWS*64
    int j = idx & 63;
    int bn = idx >> 6;                               // b*SEQ + pos
    int pos = bn & (SEQ - 1);
    const float* row = kvb + (size_t)bn * 256;
    short* orow = kb + ((size_t)bn << 7);
    float a = row[j];
    float b = row[j + 64];
    float ang = (float)pos * exp2f((float)j * NEG_LOG2_10000_DIV64);
    float c = cosf(ang), s = sinf(ang);
    orow[j]      = f2bf(a * c - b * s);
    orow[j + 64] = f2bf(b * c + a * s);
}

// ---------------------------------------------------------------------------
// V transpose + bf16 cast: kvb fp32 [b,pos,256] (v = cols 128..255)
//   -> vt bf16 [b, d(128), pos(SEQ)].  64x64 tiles via LDS.
// Grid: BATCH * 32(pos tiles) * 2(d tiles), 256 threads.
// ---------------------------------------------------------------------------
__global__ __launch_bounds__(256) void vtrans_bf16(const float* __restrict__ kvb,
                                                   short* __restrict__ vt) {
    __shared__ float tile[64][65];
    const int bb = blockIdx.x;
    const int b = bb >> 6;
    const int tile_id = bb & 63;
    const int p0 = (tile_id >> 1) * 64;
    const int d0 = (tile_id & 1) * 64;
    const int tid = threadIdx.x;

#pragma unroll
    for (int t = 0; t < 16; ++t) {
        int idx = tid + t * 256;
        int row = idx >> 6, col = idx & 63;          // row = pos, col = d
        tile[row][col] = kvb[((size_t)(b * SEQ) + p0 + row) * 256 + 128 + d0 + col];
    }
    __syncthreads();
#pragma unroll
    for (int t = 0; t < 16; ++t) {
        int idx = tid + t * 256;
        int r = idx >> 6, c = idx & 63;              // r = d, c = pos
        vt[((size_t)(b * DHEAD) + d0 + r) * SEQ + p0 + c] = f2bf(tile[c][r]);
    }
}

// ---------------------------------------------------------------------------
// MFMA flash attention (causal, MQA).
// One block (256 thr = 4 waves) per (b, h, 64-row i-tile). Wave w owns rows
// [w*16, w*16+16). j-tiles of 64 keys. mfma_f32_16x16x32_bf16 for QK^T and PV.
// Layouts (guide-verified): A/B frag [m|n = lane&15][k = (lane>>4)*8 + e];
// C/D: col = lane&15, row = (lane>>4)*4 + reg.
// LDS rows padded +8 shorts so b128 reads at 16-row stride are ~2-way (free).
// ---------------------------------------------------------------------------
#define KS_LD 136   // 128 + 8 shorts
#define VT_LD 72    // 64 + 8
#define PS_LD 72

__global__ __launch_bounds__(256) void attn_mfma(const short* __restrict__ qb,
                                                 const short* __restrict__ kb,
                                                 const short* __restrict__ vt,
                                                 float* __restrict__ o) {
    __shared__ __align__(16) short sK[64 * KS_LD];      // 17408 B
    __shared__ __align__(16) short sV[128 * VT_LD];     // 18432 B
    __shared__ __align__(16) short sP[4 * 16 * PS_LD];  //  9216 B

    const int bid = blockIdx.x;
    const int it = 31 - (bid & 31);      // heavy tiles dispatch first
    const int bh = bid >> 5;
    const int h = bh & (HEADS - 1);
    const int b = bh >> 4;
    const int i0 = it * 64;

    const int tid = threadIdx.x;
    const int w = tid >> 6;
    const int lane = tid & 63;
    const int ln = lane & 15;
    const int qr = lane >> 4;

    // preload Q A-fragments for this wave's 16 rows (stay in regs all loop)
    const size_t qrow = ((size_t)(b * SEQ + i0 + w * 16 + ln)) * INNER + h * DHEAD;
    short8 qf[4];
#pragma unroll
    for (int ks = 0; ks < 4; ++ks)
        qf[ks] = *reinterpret_cast<const short8*>(&qb[qrow + ks * 32 + qr * 8]);

    const f32x4 zero4 = {0.f, 0.f, 0.f, 0.f};
    f32x4 oacc[8];
#pragma unroll
    for (int dt = 0; dt < 8; ++dt) oacc[dt] = zero4;
    float m_run[4], l_run[4];
#pragma unroll
    for (int r = 0; r < 4; ++r) { m_run[r] = -3.0e38f; l_run[r] = 0.f; }

    const short* kbase = kb + (size_t)b * SEQ * DHEAD;
    const short* vbase = vt + (size_t)b * DHEAD * SEQ;
    short* sPw = sP + w * 16 * PS_LD;

    for (int jt = 0; jt <= it; ++jt) {
        __syncthreads();   // all waves done reading previous tile
        // stage K tile (64 x 128 bf16), 16B per thread x 4
#pragma unroll
        for (int t = 0; t < 4; ++t) {
            int u = tid + t * 256;
            int row = u >> 4, off = (u & 15) * 8;
            *reinterpret_cast<uint4*>(&sK[row * KS_LD + off]) =
                *reinterpret_cast<const uint4*>(&kbase[(size_t)(jt * 64 + row) * DHEAD + off]);
        }
        // stage Vt tile (128 x 64 bf16)
#pragma unroll
        for (int t = 0; t < 4; ++t) {
            int u = tid + t * 256;
            int row = u >> 3, off = (u & 7) * 8;
            *reinterpret_cast<uint4*>(&sV[row * VT_LD + off]) =
                *reinterpret_cast<const uint4*>(&vbase[(size_t)row * SEQ + jt * 64 + off]);
        }
        __syncthreads();

        // S = Q K^T : 16 rows x 64 cols per wave (4 n-tiles x 4 k-steps)
        f32x4 sacc[4];
#pragma unroll
        for (int nt = 0; nt < 4; ++nt) {
            sacc[nt] = zero4;
#pragma unroll
            for (int ks = 0; ks < 4; ++ks) {
                short8 kf = *reinterpret_cast<const short8*>(
                    &sK[(nt * 16 + ln) * KS_LD + ks * 32 + qr * 8]);
                sacc[nt] = __builtin_amdgcn_mfma_f32_16x16x32_bf16(qf[ks], kf, sacc[nt], 0, 0, 0);
            }
        }

        // causal mask (diagonal tile only)
        if (jt == it) {
#pragma unroll
            for (int nt = 0; nt < 4; ++nt)
#pragma unroll
                for (int r = 0; r < 4; ++r) {
                    int iloc = w * 16 + qr * 4 + r;
                    int jloc = nt * 16 + ln;
                    if (jloc > iloc) sacc[nt][r] = -3.0e38f;
                }
        }

        // online softmax (rows owned per-reg; 16-lane xor reductions)
        float mnew[4], alpha[4];
#pragma unroll
        for (int r = 0; r < 4; ++r) {
            float mx = fmaxf(fmaxf(sacc[0][r], sacc[1][r]), fmaxf(sacc[2][r], sacc[3][r]));
#pragma unroll
            for (int d = 1; d < 16; d <<= 1) mx = fmaxf(mx, __shfl_xor(mx, d));
            mnew[r] = fmaxf(m_run[r], mx);
            alpha[r] = __expf(m_run[r] - mnew[r]);   // first tile: exp(-big)=0
            m_run[r] = mnew[r];
        }
        float rs[4] = {0.f, 0.f, 0.f, 0.f};
#pragma unroll
        for (int nt = 0; nt < 4; ++nt)
#pragma unroll
            for (int r = 0; r < 4; ++r) {
                float p = __expf(sacc[nt][r] - mnew[r]);  // masked -> exp(-big)=0
                rs[r] += p;
                sPw[(qr * 4 + r) * PS_LD + nt * 16 + ln] = f2bf(p);
            }
#pragma unroll
        for (int r = 0; r < 4; ++r) {
#pragma unroll
            for (int d = 1; d < 16; d <<= 1) rs[r] += __shfl_xor(rs[r], d);
            l_run[r] = l_run[r] * alpha[r] + rs[r];
        }
#pragma unroll
        for (int dt = 0; dt < 8; ++dt)
#pragma unroll
            for (int r = 0; r < 4; ++r) oacc[dt][r] *= alpha[r];

        // PV: P (A-frag from LDS) @ Vt (B-frag, j-contiguous). Same-wave
        // write->read of sPw needs only lgkmcnt (compiler inserts it).
#pragma unroll
        for (int ks2 = 0; ks2 < 2; ++ks2) {
            short8 pf = *reinterpret_cast<const short8*>(
                &sPw[ln * PS_LD + ks2 * 32 + qr * 8]);
#pragma unroll
            for (int dt = 0; dt < 8; ++dt) {
                short8 vf = *reinterpret_cast<const short8*>(
                    &sV[(dt * 16 + ln) * VT_LD + ks2 * 32 + qr * 8]);
                oacc[dt] = __builtin_amdgcn_mfma_f32_16x16x32_bf16(pf, vf, oacc[dt], 0, 0, 0);
            }
        }
    }

    // epilogue: o = oacc / l, fp32, layout [b,pos,h*128+d]
    float invl[4];
#pragma unroll
    for (int r = 0; r < 4; ++r) invl[r] = 1.f / l_run[r];
    float* orow = o + ((size_t)(b * SEQ + i0 + w * 16 + qr * 4)) * INNER + h * DHEAD;
#pragma unroll
    for (int dt = 0; dt < 8; ++dt)
#pragma unroll
        for (int r = 0; r < 4; ++r)
            orow[(size_t)r * INNER + dt * 16 + ln] = oacc[dt][r] * invl[r];
}

// ---------------------------------------------------------------------------
extern "C" void kernel_launch(void* const* d_in, const int* in_sizes, int n_in,
                              void* d_out, int out_size, void* d_ws, size_t ws_size,
                              hipStream_t stream) {
    const float* x    = (const float*)d_in[0];   // [2, 2048, 2048]
    const float* Wq   = (const float*)d_in[1];   // [2048, 2048]
    const float* Wkv  = (const float*)d_in[2];   // [2048, 256]
    const float* Wout = (const float*)d_in[3];   // [2048, 2048]
    float* out = (float*)d_out;                  // [2, 2048, 2048]

    // workspace layout
    float* q   = (float*)d_ws;                          // MROWS*INNER fp32 (33.5 MB); reused as o after rope
    float* kvb = q + (size_t)MROWS * INNER;             // MROWS*256 fp32 (4 MB)
    short* qb  = (short*)(kvb + (size_t)MROWS * 256);   // MROWS*INNER bf16 (16.8 MB)
    short* kb  = qb + (size_t)MROWS * INNER;            // MROWS*128 bf16 (1 MB)
    short* vt  = kb + (size_t)MROWS * DHEAD;            // BATCH*128*SEQ bf16 (1 MB)
    float* o   = q;                                     // alias: q fp32 dead after rope_q

    // 1) q = x @ Wq
    sgemm64<<<dim3(INNER / BN, MROWS / BM), 256, 0, stream>>>(x, Wq, q, MROWS, INNER, DIM);
    // 2) kv = x @ Wkv
    sgemm64<<<dim3(256 / BN, MROWS / BM), 256, 0, stream>>>(x, Wkv, kvb, MROWS, 256, DIM);
    // 3) RoPE+scale+bf16 on q
    rope_q_bf16<<<(MROWS * HEADS * 64) / 256, 256, 0, stream>>>(q, qb);
    // 4) RoPE+bf16 on k
    rope_k_bf16<<<(MROWS * 64) / 256, 256, 0, stream>>>(kvb, kb);
    // 5) V transpose + bf16
    vtrans_bf16<<<BATCH * 64, 256, 0, stream>>>(kvb, vt);
    // 6) MFMA flash attention -> o (fp32, in q's space)
    attn_mfma<<<BATCH * HEADS * 32, 256, 0, stream>>>(qb, kb, vt, o);
    // 7) out = o @ Wout
    sgemm64<<<dim3(DIM / BN, MROWS / BM), 256, 0, stream>>>(o, Wout, out, MROWS, DIM, INNER);
}

// Round 3
// 448.595 us; speedup vs baseline: 12.7430x; 2.8659x over previous
//
#include <hip/hip_runtime.h>
#include <hip/hip_bf16.h>
#include <cstddef>
#include <cstdint>

// Problem constants (fixed by the reference)
#define BATCH 2
#define SEQ   2048
#define DIM   2048
#define HEADS 16
#define DHEAD 128
#define INNER (HEADS * DHEAD)   // 2048
#define MROWS (BATCH * SEQ)     // 4096
#define ATT_SCALE 0.08838834764831845f  // 128^-0.5
#define NEG_LOG2_10000_DIV64 (-13.287712379549449f / 64.0f)

typedef __attribute__((ext_vector_type(8))) short short8;  // 8 bf16 = 4 VGPRs
typedef __attribute__((ext_vector_type(4))) short short4v;
typedef __attribute__((ext_vector_type(4))) float f32x4;   // MFMA C/D

// fp32 -> bf16 round-to-nearest-even (bit-level)
static __device__ __forceinline__ short f2bf(float x) {
    uint32_t u = __float_as_uint(x);
    uint32_t r = (u + 0x7fffu + ((u >> 16) & 1u)) >> 16;
    return (short)r;
}
static __device__ __forceinline__ float bf2f(short s) {
    return __uint_as_float(((uint32_t)(uint16_t)s) << 16);
}

// async global->LDS, 16 B per lane; LDS dst = uniform base + lane*16
static __device__ __forceinline__ void glds16(const short* g, short* l) {
    __builtin_amdgcn_global_load_lds(
        (const __attribute__((address_space(1))) unsigned int*)g,
        (__attribute__((address_space(3))) unsigned int*)l, 16, 0, 0);
}

// ---------------------------------------------------------------------------
// x fp32 -> bf16 (element-wise, float4 -> short4)
// ---------------------------------------------------------------------------
__global__ __launch_bounds__(256) void cast_x(const float* __restrict__ x,
                                              short* __restrict__ xb) {
    int i = blockIdx.x * 256 + threadIdx.x;   // over MROWS*DIM/4
    float4 v = ((const float4*)x)[i];
    short4v s = {f2bf(v.x), f2bf(v.y), f2bf(v.z), f2bf(v.w)};
    ((short4v*)xb)[i] = s;
}

// ---------------------------------------------------------------------------
// W fp32 [R][C] -> Wt bf16 [C][R]  (64x64 LDS tiles)
// grid: (C/64, R/64), 256 threads
// ---------------------------------------------------------------------------
__global__ __launch_bounds__(256) void tcast(const float* __restrict__ W,
                                             short* __restrict__ Wt,
                                             int R, int C) {
    __shared__ float tile[64][65];
    const int c0 = blockIdx.x * 64, r0 = blockIdx.y * 64;
    const int tid = threadIdx.x;
#pragma unroll
    for (int t = 0; t < 16; ++t) {
        int idx = tid + t * 256;
        int row = idx >> 6, col = idx & 63;
        tile[row][col] = W[(size_t)(r0 + row) * C + c0 + col];
    }
    __syncthreads();
#pragma unroll
    for (int t = 0; t < 16; ++t) {
        int idx = tid + t * 256;
        int r = idx >> 6, c = idx & 63;
        Wt[(size_t)(c0 + r) * R + r0 + c] = f2bf(tile[c][r]);
    }
}

// ---------------------------------------------------------------------------
// bf16 MFMA GEMM (m97 structure): C[M,N] = A[M,K] @ Bt[N,K]^T
// A, Bt bf16 row-major; C fp32 or bf16 (c_bf16 flag).
// 256 thr / 4 waves; tile 128x128, BK=32; global_load_lds width-16 staging
// into unpadded row-major LDS (stride 64 B -> balanced 8/bank b128 reads).
// M,N % 128 == 0, K % 32 == 0.
// ---------------------------------------------------------------------------
__global__ __launch_bounds__(256) void gemm_bt(const short* __restrict__ A,
                                               const short* __restrict__ Bt,
                                               void* __restrict__ Cp,
                                               int M, int N, int K, int c_bf16) {
    __shared__ __align__(16) short sA[128 * 32];   // 8 KB
    __shared__ __align__(16) short sB[128 * 32];   // 8 KB

    const int tid = threadIdx.x;
    const int w = tid >> 6, lane = tid & 63;
    const int ln = lane & 15, qr = lane >> 4;
    const int bm = blockIdx.y * 128, bn = blockIdx.x * 128;
    const int wm = (w >> 1) * 64, wn = (w & 1) * 64;

    const f32x4 zero4 = {0.f, 0.f, 0.f, 0.f};
    f32x4 acc[4][4];
#pragma unroll
    for (int mt = 0; mt < 4; ++mt)
#pragma unroll
        for (int nt = 0; nt < 4; ++nt) acc[mt][nt] = zero4;

    // staging: wave w owns rows [w*32, w*32+32) of both tiles; 2 instrs each
    // of 1024 B = 16 rows; lane i -> row i>>2, 16B-chunk i&3 (matches HW
    // lds dst = base + lane*16 for row-major [row][32] layout).
    const int srow = lane >> 2;
    const int schunk = (lane & 3) * 8;
    const short* pA = A + (size_t)(bm + w * 32 + srow) * K + schunk;
    const short* pB = Bt + (size_t)(bn + w * 32 + srow) * K + schunk;
    short* lA = &sA[(w * 32) * 32];
    short* lB = &sB[(w * 32) * 32];

    for (int k0 = 0; k0 < K; k0 += 32) {
        __syncthreads();   // all waves done reading previous tile
        glds16(pA + k0, lA);
        glds16(pA + k0 + (size_t)16 * K, lA + 512);
        glds16(pB + k0, lB);
        glds16(pB + k0 + (size_t)16 * K, lB + 512);
        __syncthreads();   // drains vmcnt (glds) + barrier

        short8 af[4], bfr[4];
#pragma unroll
        for (int mt = 0; mt < 4; ++mt)
            af[mt] = *(const short8*)&sA[(wm + mt * 16 + ln) * 32 + qr * 8];
#pragma unroll
        for (int nt = 0; nt < 4; ++nt)
            bfr[nt] = *(const short8*)&sB[(wn + nt * 16 + ln) * 32 + qr * 8];
#pragma unroll
        for (int mt = 0; mt < 4; ++mt)
#pragma unroll
            for (int nt = 0; nt < 4; ++nt)
                acc[mt][nt] = __builtin_amdgcn_mfma_f32_16x16x32_bf16(
                    af[mt], bfr[nt], acc[mt][nt], 0, 0, 0);
    }

    // epilogue: C/D layout col=ln, row=qr*4+r
    if (c_bf16) {
        short* C = (short*)Cp;
#pragma unroll
        for (int mt = 0; mt < 4; ++mt)
#pragma unroll
            for (int nt = 0; nt < 4; ++nt)
#pragma unroll
                for (int r = 0; r < 4; ++r)
                    C[(size_t)(bm + wm + mt * 16 + qr * 4 + r) * N +
                      bn + wn + nt * 16 + ln] = f2bf(acc[mt][nt][r]);
    } else {
        float* C = (float*)Cp;
#pragma unroll
        for (int mt = 0; mt < 4; ++mt)
#pragma unroll
            for (int nt = 0; nt < 4; ++nt)
#pragma unroll
                for (int r = 0; r < 4; ++r)
                    C[(size_t)(bm + wm + mt * 16 + qr * 4 + r) * N +
                      bn + wn + nt * 16 + ln] = acc[mt][nt][r];
    }
}

// ---------------------------------------------------------------------------
// RoPE in-place on bf16 q [MROWS, INNER] (layout [b,pos,h,d]) with *SCALE.
// Thread handles pair (j, j+64) -> race-free in place.
// ---------------------------------------------------------------------------
__global__ __launch_bounds__(256) void rope_q_ip(short* __restrict__ qb) {
    int idx = blockIdx.x * 256 + threadIdx.x;   // over MROWS*HEADS*64
    int j = idx & 63;
    int rh = idx >> 6;                          // (b*SEQ+pos)*HEADS + h
    int pos = (rh >> 4) & (SEQ - 1);
    short* row = qb + ((size_t)rh << 7);
    float a = bf2f(row[j]);
    float b = bf2f(row[j + 64]);
    float ang = (float)pos * exp2f((float)j * NEG_LOG2_10000_DIV64);
    float c = cosf(ang), s = sinf(ang);
    row[j]      = f2bf((a * c - b * s) * ATT_SCALE);
    row[j + 64] = f2bf((b * c + a * s) * ATT_SCALE);
}

// RoPE on k: kvbb bf16 [b,pos,256] (k = cols 0..127) -> kb bf16 [b,pos,128]
__global__ __launch_bounds__(256) void rope_k_bf(const short* __restrict__ kvbb,
                                                 short* __restrict__ kb) {
    int idx = blockIdx.x * 256 + threadIdx.x;   // over MROWS*64
    int j = idx & 63;
    int bn = idx >> 6;                          // b*SEQ + pos
    int pos = bn & (SEQ - 1);
    const short* row = kvbb + (size_t)bn * 256;
    short* orow = kb + ((size_t)bn << 7);
    float a = bf2f(row[j]);
    float b = bf2f(row[j + 64]);
    float ang = (float)pos * exp2f((float)j * NEG_LOG2_10000_DIV64);
    float c = cosf(ang), s = sinf(ang);
    orow[j]      = f2bf(a * c - b * s);
    orow[j + 64] = f2bf(b * c + a * s);
}

// ---------------------------------------------------------------------------
// V transpose: kvbb bf16 [b,pos,256] (v = cols 128..255) -> vt bf16 [b,d,pos]
// ---------------------------------------------------------------------------
__global__ __launch_bounds__(256) void vtrans_bf(const short* __restrict__ kvbb,
                                                 short* __restrict__ vt) {
    __shared__ float tile[64][65];
    const int bb = blockIdx.x;
    const int b = bb >> 6;
    const int tile_id = bb & 63;
    const int p0 = (tile_id >> 1) * 64;
    const int d0 = (tile_id & 1) * 64;
    const int tid = threadIdx.x;
#pragma unroll
    for (int t = 0; t < 16; ++t) {
        int idx = tid + t * 256;
        int row = idx >> 6, col = idx & 63;   // row=pos, col=d
        tile[row][col] = bf2f(kvbb[((size_t)(b * SEQ) + p0 + row) * 256 + 128 + d0 + col]);
    }
    __syncthreads();
#pragma unroll
    for (int t = 0; t < 16; ++t) {
        int idx = tid + t * 256;
        int r = idx >> 6, c = idx & 63;       // r=d, c=pos
        vt[((size_t)(b * DHEAD) + d0 + r) * SEQ + p0 + c] = f2bf(tile[c][r]);
    }
}

// ---------------------------------------------------------------------------
// MFMA flash attention (causal, MQA) — as round 2, output bf16.
// ---------------------------------------------------------------------------
#define KS_LD 136   // 128 + 8 shorts
#define VT_LD 72    // 64 + 8
#define PS_LD 72

__global__ __launch_bounds__(256) void attn_mfma(const short* __restrict__ qb,
                                                 const short* __restrict__ kb,
                                                 const short* __restrict__ vt,
                                                 short* __restrict__ o) {
    __shared__ __align__(16) short sK[64 * KS_LD];
    __shared__ __align__(16) short sV[128 * VT_LD];
    __shared__ __align__(16) short sP[4 * 16 * PS_LD];

    const int bid = blockIdx.x;
    const int it = 31 - (bid & 31);      // heavy tiles dispatch first
    const int bh = bid >> 5;
    const int h = bh & (HEADS - 1);
    const int b = bh >> 4;
    const int i0 = it * 64;

    const int tid = threadIdx.x;
    const int w = tid >> 6;
    const int lane = tid & 63;
    const int ln = lane & 15;
    const int qr = lane >> 4;

    const size_t qrow = ((size_t)(b * SEQ + i0 + w * 16 + ln)) * INNER + h * DHEAD;
    short8 qf[4];
#pragma unroll
    for (int ks = 0; ks < 4; ++ks)
        qf[ks] = *reinterpret_cast<const short8*>(&qb[qrow + ks * 32 + qr * 8]);

    const f32x4 zero4 = {0.f, 0.f, 0.f, 0.f};
    f32x4 oacc[8];
#pragma unroll
    for (int dt = 0; dt < 8; ++dt) oacc[dt] = zero4;
    float m_run[4], l_run[4];
#pragma unroll
    for (int r = 0; r < 4; ++r) { m_run[r] = -3.0e38f; l_run[r] = 0.f; }

    const short* kbase = kb + (size_t)b * SEQ * DHEAD;
    const short* vbase = vt + (size_t)b * DHEAD * SEQ;
    short* sPw = sP + w * 16 * PS_LD;

    for (int jt = 0; jt <= it; ++jt) {
        __syncthreads();
#pragma unroll
        for (int t = 0; t < 4; ++t) {
            int u = tid + t * 256;
            int row = u >> 4, off = (u & 15) * 8;
            *reinterpret_cast<uint4*>(&sK[row * KS_LD + off]) =
                *reinterpret_cast<const uint4*>(&kbase[(size_t)(jt * 64 + row) * DHEAD + off]);
        }
#pragma unroll
        for (int t = 0; t < 4; ++t) {
            int u = tid + t * 256;
            int row = u >> 3, off = (u & 7) * 8;
            *reinterpret_cast<uint4*>(&sV[row * VT_LD + off]) =
                *reinterpret_cast<const uint4*>(&vbase[(size_t)row * SEQ + jt * 64 + off]);
        }
        __syncthreads();

        f32x4 sacc[4];
#pragma unroll
        for (int nt = 0; nt < 4; ++nt) {
            sacc[nt] = zero4;
#pragma unroll
            for (int ks = 0; ks < 4; ++ks) {
                short8 kf = *reinterpret_cast<const short8*>(
                    &sK[(nt * 16 + ln) * KS_LD + ks * 32 + qr * 8]);
                sacc[nt] = __builtin_amdgcn_mfma_f32_16x16x32_bf16(qf[ks], kf, sacc[nt], 0, 0, 0);
            }
        }

        if (jt == it) {
#pragma unroll
            for (int nt = 0; nt < 4; ++nt)
#pragma unroll
                for (int r = 0; r < 4; ++r) {
                    int iloc = w * 16 + qr * 4 + r;
                    int jloc = nt * 16 + ln;
                    if (jloc > iloc) sacc[nt][r] = -3.0e38f;
                }
        }

        float mnew[4], alpha[4];
#pragma unroll
        for (int r = 0; r < 4; ++r) {
            float mx = fmaxf(fmaxf(sacc[0][r], sacc[1][r]), fmaxf(sacc[2][r], sacc[3][r]));
#pragma unroll
            for (int d = 1; d < 16; d <<= 1) mx = fmaxf(mx, __shfl_xor(mx, d));
            mnew[r] = fmaxf(m_run[r], mx);
            alpha[r] = __expf(m_run[r] - mnew[r]);
            m_run[r] = mnew[r];
        }
        float rs[4] = {0.f, 0.f, 0.f, 0.f};
#pragma unroll
        for (int nt = 0; nt < 4; ++nt)
#pragma unroll
            for (int r = 0; r < 4; ++r) {
                float p = __expf(sacc[nt][r] - mnew[r]);
                rs[r] += p;
                sPw[(qr * 4 + r) * PS_LD + nt * 16 + ln] = f2bf(p);
            }
#pragma unroll
        for (int r = 0; r < 4; ++r) {
#pragma unroll
            for (int d = 1; d < 16; d <<= 1) rs[r] += __shfl_xor(rs[r], d);
            l_run[r] = l_run[r] * alpha[r] + rs[r];
        }
#pragma unroll
        for (int dt = 0; dt < 8; ++dt)
#pragma unroll
            for (int r = 0; r < 4; ++r) oacc[dt][r] *= alpha[r];

#pragma unroll
        for (int ks2 = 0; ks2 < 2; ++ks2) {
            short8 pf = *reinterpret_cast<const short8*>(
                &sPw[ln * PS_LD + ks2 * 32 + qr * 8]);
#pragma unroll
            for (int dt = 0; dt < 8; ++dt) {
                short8 vf = *reinterpret_cast<const short8*>(
                    &sV[(dt * 16 + ln) * VT_LD + ks2 * 32 + qr * 8]);
                oacc[dt] = __builtin_amdgcn_mfma_f32_16x16x32_bf16(pf, vf, oacc[dt], 0, 0, 0);
            }
        }
    }

    float invl[4];
#pragma unroll
    for (int r = 0; r < 4; ++r) invl[r] = 1.f / l_run[r];
    short* orow = o + ((size_t)(b * SEQ + i0 + w * 16 + qr * 4)) * INNER + h * DHEAD;
#pragma unroll
    for (int dt = 0; dt < 8; ++dt)
#pragma unroll
        for (int r = 0; r < 4; ++r)
            orow[(size_t)r * INNER + dt * 16 + ln] = f2bf(oacc[dt][r] * invl[r]);
}

// ---------------------------------------------------------------------------
extern "C" void kernel_launch(void* const* d_in, const int* in_sizes, int n_in,
                              void* d_out, int out_size, void* d_ws, size_t ws_size,
                              hipStream_t stream) {
    const float* x    = (const float*)d_in[0];   // [2, 2048, 2048]
    const float* Wq   = (const float*)d_in[1];   // [2048, 2048]
    const float* Wkv  = (const float*)d_in[2];   // [2048, 256]
    const float* Wout = (const float*)d_in[3];   // [2048, 2048]
    float* out = (float*)d_out;                  // [2, 2048, 2048]

    // workspace (bf16 shorts) — 47 MB total
    short* xb    = (short*)d_ws;                        // MROWS*DIM      16.8 MB
    short* Wt    = xb + (size_t)MROWS * DIM;            // 2048*2048       8.4 MB (Wq then Wout)
    short* Wkvt  = Wt + (size_t)DIM * INNER;            // 256*2048        1 MB
    short* qb    = Wkvt + (size_t)256 * DIM;            // MROWS*INNER    16.8 MB
    short* kvbb  = qb + (size_t)MROWS * INNER;          // MROWS*256       2 MB
    short* kb    = kvbb + (size_t)MROWS * 256;          // MROWS*128       1 MB
    short* vt    = kb + (size_t)MROWS * DHEAD;          // BATCH*128*SEQ   1 MB
    short* ob    = xb;                                  // alias: xb dead after gemm2

    // 1) casts / transposes
    cast_x<<<(MROWS * DIM / 4) / 256, 256, 0, stream>>>(x, xb);
    tcast<<<dim3(INNER / 64, DIM / 64), 256, 0, stream>>>(Wq, Wt, DIM, INNER);
    tcast<<<dim3(256 / 64, DIM / 64), 256, 0, stream>>>(Wkv, Wkvt, DIM, 256);
    // 2) q = x @ Wq (bf16 out)
    gemm_bt<<<dim3(INNER / 128, MROWS / 128), 256, 0, stream>>>(xb, Wt, qb, MROWS, INNER, DIM, 1);
    // 3) kv = x @ Wkv (bf16 out)
    gemm_bt<<<dim3(256 / 128, MROWS / 128), 256, 0, stream>>>(xb, Wkvt, kvbb, MROWS, 256, DIM, 1);
    // 4) RoPE q in-place (+scale), RoPE k -> kb, V transpose -> vt
    rope_q_ip<<<(MROWS * HEADS * 64) / 256, 256, 0, stream>>>(qb);
    rope_k_bf<<<(MROWS * 64) / 256, 256, 0, stream>>>(kvbb, kb);
    vtrans_bf<<<BATCH * 64, 256, 0, stream>>>(kvbb, vt);
    // 5) attention -> ob (bf16, aliases xb)
    attn_mfma<<<BATCH * HEADS * 32, 256, 0, stream>>>(qb, kb, vt, ob);
    // 6) Wout transpose (reuses Wt region), out = ob @ Wout (fp32 out)
    tcast<<<dim3(DIM / 64, INNER / 64), 256, 0, stream>>>(Wout, Wt, INNER, DIM);
    gemm_bt<<<dim3(DIM / 128, MROWS / 128), 256, 0, stream>>>(ob, Wt, out, MROWS, DIM, INNER, 0);
}